// Round 2
// baseline (35.200 us; speedup 1.0000x reference)
//
#include <hip/hip_runtime.h>
#include <math.h>

#define BATCH 64
#define TLEN  256
#define NCLS  2500
#define BLANK (NCLS - 1)
#define EPSF  1e-7f

// Kernel 1: per-(b,t) row argmax + max over C=2500 probs.
// Grid = B*T blocks, 256 threads each. float4 loads (625 per row).
// First-index tie-break: track (max val, min idx achieving it).
__global__ __launch_bounds__(256) void ctc_rowmax_kernel(
    const float* __restrict__ in, int* __restrict__ best, float* __restrict__ maxlp) {
  const int row = blockIdx.x;
  const float4* p4 = (const float4*)(in + (size_t)row * NCLS);
  const int tid = threadIdx.x;

  float vmax = -1.0f;  // probs are >= 0
  int   vidx = 0;

  for (int i = tid; i < NCLS / 4; i += 256) {
    float4 v = p4[i];
    int base = i << 2;
    if (v.x > vmax || (v.x == vmax && base     < vidx)) { vmax = v.x; vidx = base;     }
    if (v.y > vmax || (v.y == vmax && base + 1 < vidx)) { vmax = v.y; vidx = base + 1; }
    if (v.z > vmax || (v.z == vmax && base + 2 < vidx)) { vmax = v.z; vidx = base + 2; }
    if (v.w > vmax || (v.w == vmax && base + 3 < vidx)) { vmax = v.w; vidx = base + 3; }
  }

  // wave (64-lane) reduce: keep larger val; on tie keep smaller index
  for (int off = 32; off > 0; off >>= 1) {
    float ov = __shfl_down(vmax, off);
    int   oi = __shfl_down(vidx, off);
    if (ov > vmax || (ov == vmax && oi < vidx)) { vmax = ov; vidx = oi; }
  }

  __shared__ float s_v[4];
  __shared__ int   s_i[4];
  const int wid = tid >> 6, lane = tid & 63;
  if (lane == 0) { s_v[wid] = vmax; s_i[wid] = vidx; }
  __syncthreads();
  if (tid == 0) {
    for (int w = 1; w < 4; ++w) {
      if (s_v[w] > vmax || (s_v[w] == vmax && s_i[w] < vidx)) { vmax = s_v[w]; vidx = s_i[w]; }
    }
    best[row]  = vidx;
    maxlp[row] = logf(vmax + EPSF);
  }
}

// Kernel 2: per-batch merge-repeats/remove-blank + score.
// Grid = B blocks, T=256 threads (one per frame).
// Outputs are written as FLOAT32 (harness reads whole d_out as f32):
//   dec[B*T] = decoded labels as floats (-1.0 pad), score[B] = -(sum max logp).
__global__ __launch_bounds__(256) void ctc_decode_kernel(
    const int* __restrict__ best, const float* __restrict__ maxlp,
    float* __restrict__ dec, float* __restrict__ score) {
  const int b = blockIdx.x, t = threadIdx.x;

  __shared__ int s_best[TLEN];
  __shared__ int s_scan[TLEN];

  const int my = best[b * TLEN + t];
  s_best[t] = my;
  __syncthreads();

  const int prev = (t == 0) ? -1 : s_best[t - 1];
  const int keep = (my != BLANK && my != prev) ? 1 : 0;

  // inclusive prefix sum of keep (Hillis-Steele over 256)
  s_scan[t] = keep;
  __syncthreads();
  for (int off = 1; off < TLEN; off <<= 1) {
    int add = (t >= off) ? s_scan[t - off] : 0;
    __syncthreads();
    s_scan[t] += add;
    __syncthreads();
  }
  const int pos = s_scan[t] - 1;

  dec[b * TLEN + t] = -1.0f;
  __syncthreads();
  if (keep) dec[b * TLEN + pos] = (float)my;

  // score = -(sum of max log-probs)
  float v = maxlp[b * TLEN + t];
  for (int off = 32; off > 0; off >>= 1) v += __shfl_down(v, off);
  __shared__ float s_sum[4];
  if ((t & 63) == 0) s_sum[t >> 6] = v;
  __syncthreads();
  if (t == 0) {
    float s = s_sum[0] + s_sum[1] + s_sum[2] + s_sum[3];
    score[b] = -s;
  }
}

extern "C" void kernel_launch(void* const* d_in, const int* in_sizes, int n_in,
                              void* d_out, int out_size, void* d_ws, size_t ws_size,
                              hipStream_t stream) {
  const float* in = (const float*)d_in[0];
  float* out = (float*)d_out;                   // [B*T] decoded (as f32), then [B] scores (f32)
  int*   best  = (int*)d_ws;                    // B*T ints   (64 KiB)
  float* maxlp = (float*)((char*)d_ws + (size_t)BATCH * TLEN * sizeof(int));  // B*T floats (64 KiB)

  ctc_rowmax_kernel<<<BATCH * TLEN, 256, 0, stream>>>(in, best, maxlp);
  ctc_decode_kernel<<<BATCH, 256, 0, stream>>>(best, maxlp, out, out + BATCH * TLEN);
}

// Round 3
// 32.484 us; speedup vs baseline: 1.0836x; 1.0836x over previous
//
#include <hip/hip_runtime.h>
#include <math.h>

#define BATCH 64
#define TLEN  256
#define NCLS  2500
#define BLANK (NCLS - 1)
#define EPSF  1e-7f
#define NF4   (NCLS / 4)          // 625 float4 per row
#define FULL_IT 9                 // 9*64 = 576 float4; tail = 49
#define TAIL_LANES (NF4 - FULL_IT * 64)  // 49

// Kernel 1: one WAVE per (b,t) row. 4 waves/block, grid = B*T/4.
// Each lane loads 9-10 float4 (strided by 64), all issued before compares
// (deep MLP), then a single 64-lane shuffle reduce. No LDS, no barriers.
__global__ __launch_bounds__(256) void ctc_rowmax_kernel(
    const float* __restrict__ in, int* __restrict__ best, float* __restrict__ maxlp) {
  const int wid  = threadIdx.x >> 6;
  const int lane = threadIdx.x & 63;
  const int row  = (blockIdx.x << 2) + wid;
  const float4* __restrict__ p4 = (const float4*)(in + (size_t)row * NCLS) + lane;

  float4 v[FULL_IT + 1];
  #pragma unroll
  for (int it = 0; it < FULL_IT; ++it) v[it] = p4[it << 6];
  const bool tail = lane < TAIL_LANES;
  if (tail) v[FULL_IT] = p4[FULL_IT << 6];

  float vmax = -1.0f;   // probs >= 0
  int   vidx = 0;
  // within-lane indices are strictly increasing -> strict '>' keeps first idx
  #pragma unroll
  for (int it = 0; it < FULL_IT; ++it) {
    const int base = (it << 8) + (lane << 2);   // ((it*64+lane)*4)
    if (v[it].x > vmax) { vmax = v[it].x; vidx = base;     }
    if (v[it].y > vmax) { vmax = v[it].y; vidx = base + 1; }
    if (v[it].z > vmax) { vmax = v[it].z; vidx = base + 2; }
    if (v[it].w > vmax) { vmax = v[it].w; vidx = base + 3; }
  }
  if (tail) {
    const int base = (FULL_IT << 8) + (lane << 2);
    if (v[FULL_IT].x > vmax) { vmax = v[FULL_IT].x; vidx = base;     }
    if (v[FULL_IT].y > vmax) { vmax = v[FULL_IT].y; vidx = base + 1; }
    if (v[FULL_IT].z > vmax) { vmax = v[FULL_IT].z; vidx = base + 2; }
    if (v[FULL_IT].w > vmax) { vmax = v[FULL_IT].w; vidx = base + 3; }
  }

  // cross-lane reduce: larger value wins; tie -> smaller index
  for (int off = 32; off > 0; off >>= 1) {
    float ov = __shfl_down(vmax, off);
    int   oi = __shfl_down(vidx, off);
    if (ov > vmax || (ov == vmax && oi < vidx)) { vmax = ov; vidx = oi; }
  }
  if (lane == 0) {
    best[row]  = vidx;
    maxlp[row] = logf(vmax + EPSF);
  }
}

// Kernel 2: per-batch merge-repeats/remove-blank + score, f32 outputs.
// Grid = B blocks, T=256 threads. Shuffle wave-scan + 2 barriers.
__global__ __launch_bounds__(256) void ctc_decode_kernel(
    const int* __restrict__ best, const float* __restrict__ maxlp,
    float* __restrict__ dec, float* __restrict__ score) {
  const int b = blockIdx.x, t = threadIdx.x;
  const int lane = t & 63, wid = t >> 6;

  const int my   = best[b * TLEN + t];
  const int prev = (t == 0) ? -1 : best[b * TLEN + t - 1];  // L2-hot, cheap
  const int keep = (my != BLANK && my != prev) ? 1 : 0;

  // inclusive wave scan of keep
  int x = keep;
  #pragma unroll
  for (int off = 1; off < 64; off <<= 1) {
    int y = __shfl_up(x, off);
    if (lane >= off) x += y;
  }
  __shared__ int   s_wsum[4];
  __shared__ float s_fsum[4];
  if (lane == 63) s_wsum[wid] = x;

  // wave sum of max log-probs (overlap with scan barrier)
  float v = maxlp[b * TLEN + t];
  #pragma unroll
  for (int off = 32; off > 0; off >>= 1) v += __shfl_down(v, off);
  if (lane == 0) s_fsum[wid] = v;
  __syncthreads();

  int offset = 0;
  #pragma unroll
  for (int w = 0; w < 4; ++w) offset += (w < wid) ? s_wsum[w] : 0;
  const int pos = offset + x - 1;

  dec[b * TLEN + t] = -1.0f;
  __syncthreads();
  if (keep) dec[b * TLEN + pos] = (float)my;

  if (t == 0) score[b] = -(s_fsum[0] + s_fsum[1] + s_fsum[2] + s_fsum[3]);
}

extern "C" void kernel_launch(void* const* d_in, const int* in_sizes, int n_in,
                              void* d_out, int out_size, void* d_ws, size_t ws_size,
                              hipStream_t stream) {
  const float* in = (const float*)d_in[0];
  float* out = (float*)d_out;                   // [B*T] decoded (as f32), then [B] scores
  int*   best  = (int*)d_ws;                    // B*T ints
  float* maxlp = (float*)((char*)d_ws + (size_t)BATCH * TLEN * sizeof(int));

  ctc_rowmax_kernel<<<(BATCH * TLEN) / 4, 256, 0, stream>>>(in, best, maxlp);
  ctc_decode_kernel<<<BATCH, 256, 0, stream>>>(best, maxlp, out, out + BATCH * TLEN);
}